// Round 1
// baseline (1215.772 us; speedup 1.0000x reference)
//
#include <hip/hip_runtime.h>

#define TSTEPS 12
#define NNODES 50000
#define DIN 32
#define HDIM 128
#define DECS 7
#define MTILE 64
#define NBLK ((NNODES + MTILE - 1) / MTILE)   // 782

#define LDS_STRIDE 136   // halves per row: 128 + 8 pad -> 68 dwords, 2-way (free) bank pattern
#define XA_STRIDE 40     // 32 + 8 pad -> 20 dwords

typedef _Float16 half_t;
typedef _Float16 half8 __attribute__((ext_vector_type(8)));
typedef float float4_ __attribute__((ext_vector_type(4)));

// ---------------- workspace layout (halves then floats) ----------------
// halves: [0] WihE 65536 | [65536] WhhE | [131072] WihD | [196608] WhhD |
//         [262144] encW 4096 | [266240] fc1 8192   (total 274432 halves)
// floats at byte 548864: b_e[512], b_d[512]
#define WS_FLOAT_OFF 548864

__device__ __forceinline__ float sigmoidf_(float x) {
    return 1.0f / (1.0f + __expf(-x));
}
__device__ __forceinline__ float tanhf_(float x) {
    return fmaf(2.0f, sigmoidf_(2.0f * x), -1.0f);
}

// Pack fp32 [R,C] row-major into fragment-major fp16:
// dst[((ct*KB+kb)*64 + lane)*8 + j] = src[ct*16 + (lane&15)][kb*32 + (lane>>4)*8 + j]
__global__ void pack_weights_k(const float* __restrict__ src, half_t* __restrict__ dst,
                               int C, int KB, int total) {
    int tid = blockIdx.x * blockDim.x + threadIdx.x;
    if (tid >= total) return;
    int j    = tid & 7;
    int lane = (tid >> 3) & 63;
    int rest = tid >> 9;
    int kb   = rest % KB;
    int ct   = rest / KB;
    int row  = ct * 16 + (lane & 15);
    int col  = kb * 32 + ((lane >> 4) << 3) + j;
    dst[tid] = (half_t)src[row * C + col];
}

__global__ void prep_bias_k(const float* __restrict__ bih_e, const float* __restrict__ bhh_e,
                            const float* __restrict__ bih_d, const float* __restrict__ bhh_d,
                            float* __restrict__ be, float* __restrict__ bd) {
    int tid = blockIdx.x * blockDim.x + threadIdx.x;
    if (tid < 512) {
        be[tid] = bih_e[tid] + bhh_e[tid];
        bd[tid] = bih_d[tid] + bhh_d[tid];
    }
}

// One LSTM step for a 64-node tile. Reads A-operands (eA = input-side, hA = recurrent)
// from LDS, weights from packed global (L2-resident), writes new h (fp16) to hOut.
// Cell state cS stays in fp32 registers. Wave w owns hidden cols [32w, 32w+32).
__device__ __forceinline__ void lstm_tile_step(
    const half_t* __restrict__ eA, const half_t* __restrict__ hA, half_t* __restrict__ hOut,
    const half_t* __restrict__ Wi, const half_t* __restrict__ Wh,
    const float bR[2][4], float cS[2][4][4],
    int w, int lane, int q, int l15) {
#pragma unroll
    for (int jt = 0; jt < 2; ++jt) {
        float4_ acc[4][4];  // [gate][rt]
#pragma unroll
        for (int g = 0; g < 4; ++g)
#pragma unroll
            for (int rt = 0; rt < 4; ++rt) {
                float b = bR[jt][g];
                acc[g][rt][0] = b; acc[g][rt][1] = b; acc[g][rt][2] = b; acc[g][rt][3] = b;
            }
#pragma unroll
        for (int kb = 0; kb < 4; ++kb) {
            half8 ae[4], ah[4];
#pragma unroll
            for (int rt = 0; rt < 4; ++rt) {
                ae[rt] = *(const half8*)(eA + (rt * 16 + l15) * LDS_STRIDE + kb * 32 + q * 8);
                ah[rt] = *(const half8*)(hA + (rt * 16 + l15) * LDS_STRIDE + kb * 32 + q * 8);
            }
#pragma unroll
            for (int g = 0; g < 4; ++g) {
                int ct = g * 8 + w * 2 + jt;
                half8 bi = *(const half8*)(Wi + ((size_t)(ct * 4 + kb) * 64 + lane) * 8);
                half8 bh = *(const half8*)(Wh + ((size_t)(ct * 4 + kb) * 64 + lane) * 8);
#pragma unroll
                for (int rt = 0; rt < 4; ++rt)
                    acc[g][rt] = __builtin_amdgcn_mfma_f32_16x16x32_f16(ae[rt], bi, acc[g][rt], 0, 0, 0);
#pragma unroll
                for (int rt = 0; rt < 4; ++rt)
                    acc[g][rt] = __builtin_amdgcn_mfma_f32_16x16x32_f16(ah[rt], bh, acc[g][rt], 0, 0, 0);
            }
        }
        // cell update in C-layout: row = rt*16 + q*4 + r, col = w*32 + jt*16 + l15
#pragma unroll
        for (int rt = 0; rt < 4; ++rt) {
#pragma unroll
            for (int r = 0; r < 4; ++r) {
                float iv = sigmoidf_(acc[0][rt][r]);
                float fv = sigmoidf_(acc[1][rt][r]);
                float gv = tanhf_(acc[2][rt][r]);
                float ov = sigmoidf_(acc[3][rt][r]);
                float c  = fv * cS[jt][rt][r] + iv * gv;
                cS[jt][rt][r] = c;
                float h = ov * tanhf_(c);
                hOut[(rt * 16 + q * 4 + r) * LDS_STRIDE + w * 32 + jt * 16 + l15] = (half_t)h;
            }
        }
    }
}

__global__ __launch_bounds__(256, 2) void seq2seq_main_k(
    const float* __restrict__ x,
    const float* __restrict__ enc_b,
    const float* __restrict__ fc1_b,
    const float* __restrict__ fc2_W,
    const float* __restrict__ fc2_b,
    const half_t* __restrict__ wsh,
    const float* __restrict__ be,
    const float* __restrict__ bd,
    float* __restrict__ out) {
    __shared__ __align__(16) half_t xa[MTILE * XA_STRIDE];
    __shared__ __align__(16) half_t e_lds[MTILE * LDS_STRIDE];
    __shared__ __align__(16) half_t h_lds[2][MTILE * LDS_STRIDE];
    __shared__ float pred_lds[4][MTILE];

    const int tid  = threadIdx.x;
    const int lane = tid & 63;
    const int w    = tid >> 6;
    const int q    = lane >> 4;
    const int l15  = lane & 15;
    const int n0   = blockIdx.x * MTILE;

    const half_t* WihE  = wsh;
    const half_t* WhhE  = wsh + 65536;
    const half_t* WihD  = wsh + 131072;
    const half_t* WhhD  = wsh + 196608;
    const half_t* encWp = wsh + 262144;
    const half_t* fc1p  = wsh + 266240;

    // per-wave bias registers
    float beR[2][4], bdR[2][4];
#pragma unroll
    for (int jt = 0; jt < 2; ++jt)
#pragma unroll
        for (int g = 0; g < 4; ++g) {
            int col = g * 128 + w * 32 + jt * 16 + l15;
            beR[jt][g] = be[col];
            bdR[jt][g] = bd[col];
        }
    float bencR[2];
#pragma unroll
    for (int ci = 0; ci < 2; ++ci) bencR[ci] = enc_b[(2 * w + ci) * 16 + l15];
    float bf1 = fc1_b[w * 16 + l15];
    float wf2 = fc2_W[w * 16 + l15];
    float bf2 = fc2_b[0];

    // zero initial h
    for (int i = tid; i < MTILE * LDS_STRIDE; i += 256) h_lds[0][i] = (half_t)0.0f;

    float c_reg[2][4][4];
#pragma unroll
    for (int jt = 0; jt < 2; ++jt)
#pragma unroll
        for (int rt = 0; rt < 4; ++rt)
#pragma unroll
            for (int r = 0; r < 4; ++r) c_reg[jt][rt][r] = 0.0f;

    int cur = 0;

    // ================= encoder =================
    for (int t = 0; t < TSTEPS; ++t) {
        __syncthreads();  // prev-step LDS reads done
        // stage x_t tile [64 x 32] fp32 -> fp16 LDS (coalesced 8KB contiguous)
        {
            int row = tid >> 2;
            int c0  = (tid & 3) * 8;
            int n   = n0 + row;
            float4_ a0 = {0.f, 0.f, 0.f, 0.f}, a1 = {0.f, 0.f, 0.f, 0.f};
            if (n < NNODES) {
                const float* p = x + ((size_t)t * NNODES + n) * DIN + c0;
                a0 = *(const float4_*)p;
                a1 = *(const float4_*)(p + 4);
            }
            half8 hv;
            hv[0] = (half_t)a0[0]; hv[1] = (half_t)a0[1]; hv[2] = (half_t)a0[2]; hv[3] = (half_t)a0[3];
            hv[4] = (half_t)a1[0]; hv[5] = (half_t)a1[1]; hv[6] = (half_t)a1[2]; hv[7] = (half_t)a1[3];
            *(half8*)(xa + row * XA_STRIDE + c0) = hv;
        }
        __syncthreads();  // xa ready
        // e_t = relu(x_t @ encW^T + enc_b); wave w computes col-tiles {2w, 2w+1}
#pragma unroll
        for (int ci = 0; ci < 2; ++ci) {
            int ct = 2 * w + ci;
            half8 bfrag = *(const half8*)(encWp + (size_t)ct * 512 + lane * 8);
#pragma unroll
            for (int rt = 0; rt < 4; ++rt) {
                half8 afrag = *(const half8*)(xa + (rt * 16 + l15) * XA_STRIDE + q * 8);
                float4_ acc;
                acc[0] = bencR[ci]; acc[1] = bencR[ci]; acc[2] = bencR[ci]; acc[3] = bencR[ci];
                acc = __builtin_amdgcn_mfma_f32_16x16x32_f16(afrag, bfrag, acc, 0, 0, 0);
#pragma unroll
                for (int r = 0; r < 4; ++r) {
                    float v = acc[r];
                    v = v > 0.f ? v : 0.f;
                    e_lds[(rt * 16 + q * 4 + r) * LDS_STRIDE + ct * 16 + l15] = (half_t)v;
                }
            }
        }
        __syncthreads();  // e ready, h[cur] ready
        lstm_tile_step(e_lds, h_lds[cur], h_lds[cur ^ 1], WihE, WhhE, beR, c_reg, w, lane, q, l15);
        cur ^= 1;
    }

    // d_in = final encoder h (fixed for all decoder steps): copy h[cur] -> e_lds
    __syncthreads();
    for (int i = tid; i < MTILE * 64; i += 256) {
        int row = i >> 6, dc = i & 63;
        ((unsigned int*)(e_lds + row * LDS_STRIDE))[dc] =
            ((const unsigned int*)(h_lds[cur] + row * LDS_STRIDE))[dc];
    }
    __syncthreads();

    // ================= decoder =================
    for (int s = 0; s < DECS; ++s) {
        lstm_tile_step(e_lds, h_lds[cur], h_lds[cur ^ 1], WihD, WhhD, bdR, c_reg, w, lane, q, l15);
        cur ^= 1;
        __syncthreads();  // new h ready
        // head: o64 = relu(h @ fc1^T + b1); pred = o64 @ fc2^T + b2. Wave w: fc1 cols [16w,16w+16)
        float4_ hacc[4];
#pragma unroll
        for (int rt = 0; rt < 4; ++rt) {
            hacc[rt][0] = bf1; hacc[rt][1] = bf1; hacc[rt][2] = bf1; hacc[rt][3] = bf1;
        }
#pragma unroll
        for (int kb = 0; kb < 4; ++kb) {
            half8 bfr = *(const half8*)(fc1p + ((size_t)(w * 4 + kb) * 64 + lane) * 8);
#pragma unroll
            for (int rt = 0; rt < 4; ++rt) {
                half8 af = *(const half8*)(h_lds[cur] + (rt * 16 + l15) * LDS_STRIDE + kb * 32 + q * 8);
                hacc[rt] = __builtin_amdgcn_mfma_f32_16x16x32_f16(af, bfr, hacc[rt], 0, 0, 0);
            }
        }
        float red[4][4];
#pragma unroll
        for (int rt = 0; rt < 4; ++rt) {
#pragma unroll
            for (int r = 0; r < 4; ++r) {
                float v = hacc[rt][r];
                v = v > 0.f ? v : 0.f;
                v *= wf2;
                v += __shfl_xor(v, 1, 64);
                v += __shfl_xor(v, 2, 64);
                v += __shfl_xor(v, 4, 64);
                v += __shfl_xor(v, 8, 64);
                red[rt][r] = v;
            }
        }
        if (l15 == 0) {
#pragma unroll
            for (int rt = 0; rt < 4; ++rt)
#pragma unroll
                for (int r = 0; r < 4; ++r) pred_lds[w][rt * 16 + q * 4 + r] = red[rt][r];
        }
        __syncthreads();
        if (tid < MTILE) {
            float sum = pred_lds[0][tid] + pred_lds[1][tid] + pred_lds[2][tid] + pred_lds[3][tid] + bf2;
            int n = n0 + tid;
            if (n < NNODES) out[(size_t)n * DECS + s] = sum;
        }
        __syncthreads();
    }
}

extern "C" void kernel_launch(void* const* d_in, const int* in_sizes, int n_in,
                              void* d_out, int out_size, void* d_ws, size_t ws_size,
                              hipStream_t stream) {
    (void)in_sizes; (void)n_in; (void)out_size; (void)ws_size;
    const float* x     = (const float*)d_in[0];
    const float* enc_W = (const float*)d_in[1];
    const float* enc_b = (const float*)d_in[2];
    const float* Wih_e = (const float*)d_in[3];
    const float* Whh_e = (const float*)d_in[4];
    const float* bih_e = (const float*)d_in[5];
    const float* bhh_e = (const float*)d_in[6];
    const float* Wih_d = (const float*)d_in[7];
    const float* Whh_d = (const float*)d_in[8];
    const float* bih_d = (const float*)d_in[9];
    const float* bhh_d = (const float*)d_in[10];
    const float* fc1_W = (const float*)d_in[11];
    const float* fc1_b = (const float*)d_in[12];
    const float* fc2_W = (const float*)d_in[13];
    const float* fc2_b = (const float*)d_in[14];

    half_t* wsh = (half_t*)d_ws;
    float*  be  = (float*)((char*)d_ws + WS_FLOAT_OFF);
    float*  bd  = be + 512;

    pack_weights_k<<<256, 256, 0, stream>>>(Wih_e, wsh + 0,      128, 4, 65536);
    pack_weights_k<<<256, 256, 0, stream>>>(Whh_e, wsh + 65536,  128, 4, 65536);
    pack_weights_k<<<256, 256, 0, stream>>>(Wih_d, wsh + 131072, 128, 4, 65536);
    pack_weights_k<<<256, 256, 0, stream>>>(Whh_d, wsh + 196608, 128, 4, 65536);
    pack_weights_k<<<16,  256, 0, stream>>>(enc_W, wsh + 262144, 32,  1, 4096);
    pack_weights_k<<<32,  256, 0, stream>>>(fc1_W, wsh + 266240, 128, 4, 8192);
    prep_bias_k<<<2, 256, 0, stream>>>(bih_e, bhh_e, bih_d, bhh_d, be, bd);

    seq2seq_main_k<<<NBLK, 256, 0, stream>>>(x, enc_b, fc1_b, fc2_W, fc2_b,
                                             wsh, be, bd, (float*)d_out);
}

// Round 2
// 1115.105 us; speedup vs baseline: 1.0903x; 1.0903x over previous
//
#include <hip/hip_runtime.h>

#define TSTEPS 12
#define NNODES 50000
#define DIN 32
#define HDIM 128
#define DECS 7
#define MTILE 64
#define NBLK ((NNODES + MTILE - 1) / MTILE)   // 782

#define HS 140   // halves per row for e/h buffers (70 dwords; lane-row bank step 6 -> conflict-free)
#define XS 36    // halves per row per timestep for x tile

typedef _Float16 half_t;
typedef _Float16 half8 __attribute__((ext_vector_type(8)));
typedef float float4_ __attribute__((ext_vector_type(4)));

// ---------------- workspace layout (halves then floats) ----------------
// halves: [0] WihE 65536 | [65536] WhhE | [131072] WihD | [196608] WhhD |
//         [262144] encW 4096 | [266240] fc1 8192   (total 274432 halves)
// floats at byte 548864: b_e[512], b_d[512]
#define WS_FLOAT_OFF 548864

__device__ __forceinline__ float sigmoidf_(float x) {
    return 1.0f / (1.0f + __expf(-x));
}
__device__ __forceinline__ float tanhf_(float x) {
    return fmaf(2.0f, sigmoidf_(2.0f * x), -1.0f);
}

// Pack fp32 [R,C] row-major into fragment-major fp16 (B-operand layout):
// dst[((ct*KB+kb)*64 + lane)*8 + j] = src[ct*16 + (lane&15)][kb*32 + (lane>>4)*8 + j]
__global__ void pack_weights_k(const float* __restrict__ src, half_t* __restrict__ dst,
                               int C, int KB, int total) {
    int tid = blockIdx.x * blockDim.x + threadIdx.x;
    if (tid >= total) return;
    int j    = tid & 7;
    int lane = (tid >> 3) & 63;
    int rest = tid >> 9;
    int kb   = rest % KB;
    int ct   = rest / KB;
    int row  = ct * 16 + (lane & 15);
    int col  = kb * 32 + ((lane >> 4) << 3) + j;
    dst[tid] = (half_t)src[row * C + col];
}

__global__ void prep_bias_k(const float* __restrict__ bih_e, const float* __restrict__ bhh_e,
                            const float* __restrict__ bih_d, const float* __restrict__ bhh_d,
                            float* __restrict__ be, float* __restrict__ bd) {
    int tid = blockIdx.x * blockDim.x + threadIdx.x;
    if (tid < 512) {
        be[tid] = bih_e[tid] + bhh_e[tid];
        bd[tid] = bih_d[tid] + bhh_d[tid];
    }
}

// LSTM step with register-resident weights. eA/hA read from LDS; new h -> hOut (LDS).
// Wave w owns hidden cols [32w, 32w+32). Cell state in fp32 regs.
__device__ __forceinline__ void lstm_tile_step(
    const half_t* __restrict__ eA, const half_t* __restrict__ hA, half_t* __restrict__ hOut,
    const half8 (&wfi)[2][4][4], const half8 (&wfh)[2][4][4],
    const float bR[2][4], float cS[2][4][4],
    int w, int q, int l15) {
#pragma unroll
    for (int jt = 0; jt < 2; ++jt) {
        float4_ acc[4][4];  // [gate][rt]
#pragma unroll
        for (int g = 0; g < 4; ++g)
#pragma unroll
            for (int rt = 0; rt < 4; ++rt) {
                float b = bR[jt][g];
                acc[g][rt][0] = b; acc[g][rt][1] = b; acc[g][rt][2] = b; acc[g][rt][3] = b;
            }
#pragma unroll
        for (int kb = 0; kb < 4; ++kb) {
            half8 ae[4], ah[4];
#pragma unroll
            for (int rt = 0; rt < 4; ++rt) {
                ae[rt] = *(const half8*)(eA + (rt * 16 + l15) * HS + kb * 32 + q * 8);
                ah[rt] = *(const half8*)(hA + (rt * 16 + l15) * HS + kb * 32 + q * 8);
            }
#pragma unroll
            for (int g = 0; g < 4; ++g) {
#pragma unroll
                for (int rt = 0; rt < 4; ++rt)
                    acc[g][rt] = __builtin_amdgcn_mfma_f32_16x16x32_f16(ae[rt], wfi[jt][g][kb], acc[g][rt], 0, 0, 0);
#pragma unroll
                for (int rt = 0; rt < 4; ++rt)
                    acc[g][rt] = __builtin_amdgcn_mfma_f32_16x16x32_f16(ah[rt], wfh[jt][g][kb], acc[g][rt], 0, 0, 0);
            }
        }
        // cell update in C-layout: row = rt*16 + q*4 + r, col = w*32 + jt*16 + l15
#pragma unroll
        for (int rt = 0; rt < 4; ++rt) {
#pragma unroll
            for (int r = 0; r < 4; ++r) {
                float iv = sigmoidf_(acc[0][rt][r]);
                float fv = sigmoidf_(acc[1][rt][r]);
                float gv = tanhf_(acc[2][rt][r]);
                float ov = sigmoidf_(acc[3][rt][r]);
                float c  = fv * cS[jt][rt][r] + iv * gv;
                cS[jt][rt][r] = c;
                float h = ov * tanhf_(c);
                hOut[(rt * 16 + q * 4 + r) * HS + w * 32 + jt * 16 + l15] = (half_t)h;
            }
        }
    }
}

__global__ __launch_bounds__(256, 1) void seq2seq_main_k(
    const float* __restrict__ x,
    const float* __restrict__ enc_b,
    const float* __restrict__ fc1_b,
    const float* __restrict__ fc2_W,
    const float* __restrict__ fc2_b,
    const half_t* __restrict__ wsh,
    const float* __restrict__ be,
    const float* __restrict__ bd,
    float* __restrict__ out) {
    __shared__ __align__(16) half_t xa[TSTEPS * MTILE * XS];   // 55296 B
    __shared__ __align__(16) half_t e_lds[2][MTILE * HS];      // 35840 B
    __shared__ __align__(16) half_t h_lds[2][MTILE * HS];      // 35840 B
    __shared__ float pred_lds[4][MTILE];                       // 1024 B

    const int tid  = threadIdx.x;
    const int lane = tid & 63;
    const int w    = tid >> 6;
    const int q    = lane >> 4;
    const int l15  = lane & 15;
    const int n0   = blockIdx.x * MTILE;

    const half_t* WihE  = wsh;
    const half_t* WhhE  = wsh + 65536;
    const half_t* WihD  = wsh + 131072;
    const half_t* WhhD  = wsh + 196608;
    const half_t* encWp = wsh + 262144;
    const half_t* fc1p  = wsh + 266240;

    // per-wave bias registers
    float beR[2][4], bdR[2][4];
#pragma unroll
    for (int jt = 0; jt < 2; ++jt)
#pragma unroll
        for (int g = 0; g < 4; ++g) {
            int col = g * 128 + w * 32 + jt * 16 + l15;
            beR[jt][g] = be[col];
            bdR[jt][g] = bd[col];
        }
    float bencR[2];
#pragma unroll
    for (int ci = 0; ci < 2; ++ci) bencR[ci] = enc_b[(2 * w + ci) * 16 + l15];

    // stage ALL x timesteps for this tile into LDS (fp16), one-time
    {
        int row = tid >> 2;
        int c0  = (tid & 3) * 8;
        int n   = n0 + row;
#pragma unroll
        for (int t = 0; t < TSTEPS; ++t) {
            float4_ a0 = {0.f, 0.f, 0.f, 0.f}, a1 = {0.f, 0.f, 0.f, 0.f};
            if (n < NNODES) {
                const float* p = x + ((size_t)t * NNODES + n) * DIN + c0;
                a0 = *(const float4_*)p;
                a1 = *(const float4_*)(p + 4);
            }
            half8 hv;
            hv[0] = (half_t)a0[0]; hv[1] = (half_t)a0[1]; hv[2] = (half_t)a0[2]; hv[3] = (half_t)a0[3];
            hv[4] = (half_t)a1[0]; hv[5] = (half_t)a1[1]; hv[6] = (half_t)a1[2]; hv[7] = (half_t)a1[3];
            *(half8*)(xa + (t * MTILE + row) * XS + c0) = hv;
        }
    }

    // zero initial h
    for (int i = tid; i < MTILE * HS; i += 256) h_lds[0][i] = (half_t)0.0f;

    float c_reg[2][4][4];
#pragma unroll
    for (int jt = 0; jt < 2; ++jt)
#pragma unroll
        for (int rt = 0; rt < 4; ++rt)
#pragma unroll
            for (int r = 0; r < 4; ++r) c_reg[jt][rt][r] = 0.0f;

    // ---- encoder weights into registers (per-wave slice: 256 VGPRs) ----
    half8 wfi[2][4][4], wfh[2][4][4];
#pragma unroll
    for (int jt = 0; jt < 2; ++jt)
#pragma unroll
        for (int g = 0; g < 4; ++g)
#pragma unroll
            for (int kb = 0; kb < 4; ++kb) {
                int ct = g * 8 + w * 2 + jt;
                wfi[jt][g][kb] = *(const half8*)(WihE + ((size_t)(ct * 4 + kb) * 64 + lane) * 8);
                wfh[jt][g][kb] = *(const half8*)(WhhE + ((size_t)(ct * 4 + kb) * 64 + lane) * 8);
            }
    half8 encWf[2];
#pragma unroll
    for (int ci = 0; ci < 2; ++ci)
        encWf[ci] = *(const half8*)(encWp + (size_t)(2 * w + ci) * 512 + lane * 8);

    __syncthreads();  // xa + h0 ready

    // e(0)
#pragma unroll
    for (int ci = 0; ci < 2; ++ci) {
        int ct = 2 * w + ci;
#pragma unroll
        for (int rt = 0; rt < 4; ++rt) {
            half8 afrag = *(const half8*)(xa + (0 * MTILE + rt * 16 + l15) * XS + q * 8);
            float4_ acc;
            acc[0] = bencR[ci]; acc[1] = bencR[ci]; acc[2] = bencR[ci]; acc[3] = bencR[ci];
            acc = __builtin_amdgcn_mfma_f32_16x16x32_f16(afrag, encWf[ci], acc, 0, 0, 0);
#pragma unroll
            for (int r = 0; r < 4; ++r) {
                float v = acc[r];
                v = v > 0.f ? v : 0.f;
                e_lds[0][(rt * 16 + q * 4 + r) * HS + ct * 16 + l15] = (half_t)v;
            }
        }
    }
    __syncthreads();  // e0 ready

    int cur = 0;
    // ================= encoder: ONE barrier per step =================
    for (int t = 0; t < TSTEPS; ++t) {
        lstm_tile_step(e_lds[t & 1], h_lds[cur], h_lds[cur ^ 1], wfi, wfh, beR, c_reg, w, q, l15);
        if (t + 1 < TSTEPS) {
            // compute e(t+1) into the other e buffer (no hazard with this step's reads)
#pragma unroll
            for (int ci = 0; ci < 2; ++ci) {
                int ct = 2 * w + ci;
#pragma unroll
                for (int rt = 0; rt < 4; ++rt) {
                    half8 afrag = *(const half8*)(xa + ((t + 1) * MTILE + rt * 16 + l15) * XS + q * 8);
                    float4_ acc;
                    acc[0] = bencR[ci]; acc[1] = bencR[ci]; acc[2] = bencR[ci]; acc[3] = bencR[ci];
                    acc = __builtin_amdgcn_mfma_f32_16x16x32_f16(afrag, encWf[ci], acc, 0, 0, 0);
#pragma unroll
                    for (int r = 0; r < 4; ++r) {
                        float v = acc[r];
                        v = v > 0.f ? v : 0.f;
                        e_lds[(t & 1) ^ 1][(rt * 16 + q * 4 + r) * HS + ct * 16 + l15] = (half_t)v;
                    }
                }
            }
        }
        __syncthreads();
        cur ^= 1;
    }

    // ---- decoder weights into the same registers; head params ----
#pragma unroll
    for (int jt = 0; jt < 2; ++jt)
#pragma unroll
        for (int g = 0; g < 4; ++g)
#pragma unroll
            for (int kb = 0; kb < 4; ++kb) {
                int ct = g * 8 + w * 2 + jt;
                wfi[jt][g][kb] = *(const half8*)(WihD + ((size_t)(ct * 4 + kb) * 64 + lane) * 8);
                wfh[jt][g][kb] = *(const half8*)(WhhD + ((size_t)(ct * 4 + kb) * 64 + lane) * 8);
            }
    half8 fc1f[4];
#pragma unroll
    for (int kb = 0; kb < 4; ++kb)
        fc1f[kb] = *(const half8*)(fc1p + ((size_t)(w * 4 + kb) * 64 + lane) * 8);
    float bf1 = fc1_b[w * 16 + l15];
    float wf2 = fc2_W[w * 16 + l15];
    float bf2 = fc2_b[0];

    // d_in = final encoder h (fixed across decoder steps): copy h[cur] -> e_lds[0]
    for (int i = tid; i < MTILE * 64; i += 256) {
        int row = i >> 6, dc = i & 63;
        ((unsigned int*)(e_lds[0] + row * HS))[dc] =
            ((const unsigned int*)(h_lds[cur] + row * HS))[dc];
    }
    __syncthreads();

    // ================= decoder =================
    for (int s = 0; s < DECS; ++s) {
        lstm_tile_step(e_lds[0], h_lds[cur], h_lds[cur ^ 1], wfi, wfh, bdR, c_reg, w, q, l15);
        cur ^= 1;
        __syncthreads();  // new h ready
        // head: o64 = relu(h @ fc1^T + b1); pred = o64 @ fc2^T + b2
        float4_ hacc[4];
#pragma unroll
        for (int rt = 0; rt < 4; ++rt) {
            hacc[rt][0] = bf1; hacc[rt][1] = bf1; hacc[rt][2] = bf1; hacc[rt][3] = bf1;
        }
#pragma unroll
        for (int kb = 0; kb < 4; ++kb) {
#pragma unroll
            for (int rt = 0; rt < 4; ++rt) {
                half8 af = *(const half8*)(h_lds[cur] + (rt * 16 + l15) * HS + kb * 32 + q * 8);
                hacc[rt] = __builtin_amdgcn_mfma_f32_16x16x32_f16(af, fc1f[kb], hacc[rt], 0, 0, 0);
            }
        }
        float red[4][4];
#pragma unroll
        for (int rt = 0; rt < 4; ++rt) {
#pragma unroll
            for (int r = 0; r < 4; ++r) {
                float v = hacc[rt][r];
                v = v > 0.f ? v : 0.f;
                v *= wf2;
                v += __shfl_xor(v, 1, 64);
                v += __shfl_xor(v, 2, 64);
                v += __shfl_xor(v, 4, 64);
                v += __shfl_xor(v, 8, 64);
                red[rt][r] = v;
            }
        }
        if (l15 == 0) {
#pragma unroll
            for (int rt = 0; rt < 4; ++rt)
#pragma unroll
                for (int r = 0; r < 4; ++r) pred_lds[w][rt * 16 + q * 4 + r] = red[rt][r];
        }
        __syncthreads();
        if (tid < MTILE) {
            float sum = pred_lds[0][tid] + pred_lds[1][tid] + pred_lds[2][tid] + pred_lds[3][tid] + bf2;
            int n = n0 + tid;
            if (n < NNODES) out[(size_t)n * DECS + s] = sum;
        }
        // no trailing barrier needed: next head's pred_lds write is ordered
        // behind the next lstm step's __syncthreads()
    }
}

extern "C" void kernel_launch(void* const* d_in, const int* in_sizes, int n_in,
                              void* d_out, int out_size, void* d_ws, size_t ws_size,
                              hipStream_t stream) {
    (void)in_sizes; (void)n_in; (void)out_size; (void)ws_size;
    const float* x     = (const float*)d_in[0];
    const float* enc_W = (const float*)d_in[1];
    const float* enc_b = (const float*)d_in[2];
    const float* Wih_e = (const float*)d_in[3];
    const float* Whh_e = (const float*)d_in[4];
    const float* bih_e = (const float*)d_in[5];
    const float* bhh_e = (const float*)d_in[6];
    const float* Wih_d = (const float*)d_in[7];
    const float* Whh_d = (const float*)d_in[8];
    const float* bih_d = (const float*)d_in[9];
    const float* bhh_d = (const float*)d_in[10];
    const float* fc1_W = (const float*)d_in[11];
    const float* fc1_b = (const float*)d_in[12];
    const float* fc2_W = (const float*)d_in[13];
    const float* fc2_b = (const float*)d_in[14];

    half_t* wsh = (half_t*)d_ws;
    float*  be  = (float*)((char*)d_ws + WS_FLOAT_OFF);
    float*  bd  = be + 512;

    pack_weights_k<<<256, 256, 0, stream>>>(Wih_e, wsh + 0,      128, 4, 65536);
    pack_weights_k<<<256, 256, 0, stream>>>(Whh_e, wsh + 65536,  128, 4, 65536);
    pack_weights_k<<<256, 256, 0, stream>>>(Wih_d, wsh + 131072, 128, 4, 65536);
    pack_weights_k<<<256, 256, 0, stream>>>(Whh_d, wsh + 196608, 128, 4, 65536);
    pack_weights_k<<<16,  256, 0, stream>>>(enc_W, wsh + 262144, 32,  1, 4096);
    pack_weights_k<<<32,  256, 0, stream>>>(fc1_W, wsh + 266240, 128, 4, 8192);
    prep_bias_k<<<2, 256, 0, stream>>>(bih_e, bhh_e, bih_d, bhh_d, be, bd);

    seq2seq_main_k<<<NBLK, 256, 0, stream>>>(x, enc_b, fc1_b, fc2_W, fc2_b,
                                             wsh, be, bd, (float*)d_out);
}

// Round 3
// 971.474 us; speedup vs baseline: 1.2515x; 1.1478x over previous
//
#include <hip/hip_runtime.h>

#define TSTEPS 12
#define NNODES 50000
#define DIN 32
#define HDIM 128
#define DECS 7
#define MTILE 32
#define NTILES ((NNODES + MTILE - 1) / MTILE)   // 1563

#define HS 140   // halves per row for e/h buffers; row stride 70 dwords -> uniform 2-way banks (free)
#define XS 36    // halves per row per timestep for x tile

typedef _Float16 half_t;
typedef _Float16 half8 __attribute__((ext_vector_type(8)));
typedef float float4_ __attribute__((ext_vector_type(4)));

// ---------------- workspace layout (halves then floats) ----------------
// halves: [0] WihE 65536 | [65536] WhhE | [131072] WihD | [196608] WhhD |
//         [262144] encW 4096 | [266240] fc1 8192   (total 274432 halves)
// floats at byte 548864: b_e[512], b_d[512]
#define WS_FLOAT_OFF 548864

__device__ __forceinline__ float sigmoidf_(float x) {
    return 1.0f / (1.0f + __expf(-x));
}
__device__ __forceinline__ float tanhf_(float x) {
    return fmaf(2.0f, sigmoidf_(2.0f * x), -1.0f);
}

// Pack fp32 [R,C] row-major into fragment-major fp16 (B-operand layout):
// dst[((ct*KB+kb)*64 + lane)*8 + j] = src[ct*16 + (lane&15)][kb*32 + (lane>>4)*8 + j]
__global__ void pack_weights_k(const float* __restrict__ src, half_t* __restrict__ dst,
                               int C, int KB, int total) {
    int tid = blockIdx.x * blockDim.x + threadIdx.x;
    if (tid >= total) return;
    int j    = tid & 7;
    int lane = (tid >> 3) & 63;
    int rest = tid >> 9;
    int kb   = rest % KB;
    int ct   = rest / KB;
    int row  = ct * 16 + (lane & 15);
    int col  = kb * 32 + ((lane >> 4) << 3) + j;
    dst[tid] = (half_t)src[row * C + col];
}

__global__ void prep_bias_k(const float* __restrict__ bih_e, const float* __restrict__ bhh_e,
                            const float* __restrict__ bih_d, const float* __restrict__ bhh_d,
                            float* __restrict__ be, float* __restrict__ bd) {
    int tid = blockIdx.x * blockDim.x + threadIdx.x;
    if (tid < 512) {
        be[tid] = bih_e[tid] + bhh_e[tid];
        bd[tid] = bih_d[tid] + bhh_d[tid];
    }
}

// LSTM step for a 32-node tile, 8 waves. Wave w owns cols [16w,16w+16) of each gate.
// Weights register-resident: wfi/wfh[gate][kb], 128 VGPRs total.
__device__ __forceinline__ void lstm_step32(
    const half_t* __restrict__ eA, const half_t* __restrict__ hA, half_t* __restrict__ hOut,
    const half8 (&wfi)[4][4], const half8 (&wfh)[4][4],
    const float bR[4], float cS[2][4],
    int w, int q, int l15) {
    float4_ acc[4][2];  // [gate][rt]
#pragma unroll
    for (int g = 0; g < 4; ++g)
#pragma unroll
        for (int rt = 0; rt < 2; ++rt) {
            float b = bR[g];
            acc[g][rt][0] = b; acc[g][rt][1] = b; acc[g][rt][2] = b; acc[g][rt][3] = b;
        }
#pragma unroll
    for (int kb = 0; kb < 4; ++kb) {
        half8 ae0 = *(const half8*)(eA + (l15)      * HS + kb * 32 + q * 8);
        half8 ae1 = *(const half8*)(eA + (16 + l15) * HS + kb * 32 + q * 8);
        half8 ah0 = *(const half8*)(hA + (l15)      * HS + kb * 32 + q * 8);
        half8 ah1 = *(const half8*)(hA + (16 + l15) * HS + kb * 32 + q * 8);
#pragma unroll
        for (int g = 0; g < 4; ++g) {
            acc[g][0] = __builtin_amdgcn_mfma_f32_16x16x32_f16(ae0, wfi[g][kb], acc[g][0], 0, 0, 0);
            acc[g][1] = __builtin_amdgcn_mfma_f32_16x16x32_f16(ae1, wfi[g][kb], acc[g][1], 0, 0, 0);
            acc[g][0] = __builtin_amdgcn_mfma_f32_16x16x32_f16(ah0, wfh[g][kb], acc[g][0], 0, 0, 0);
            acc[g][1] = __builtin_amdgcn_mfma_f32_16x16x32_f16(ah1, wfh[g][kb], acc[g][1], 0, 0, 0);
        }
    }
    // C-layout: row = rt*16 + q*4 + r, col (within H) = w*16 + l15
#pragma unroll
    for (int rt = 0; rt < 2; ++rt) {
#pragma unroll
        for (int r = 0; r < 4; ++r) {
            float iv = sigmoidf_(acc[0][rt][r]);
            float fv = sigmoidf_(acc[1][rt][r]);
            float gv = tanhf_(acc[2][rt][r]);
            float ov = sigmoidf_(acc[3][rt][r]);
            float c  = fv * cS[rt][r] + iv * gv;
            cS[rt][r] = c;
            float h = ov * tanhf_(c);
            hOut[(rt * 16 + q * 4 + r) * HS + w * 16 + l15] = (half_t)h;
        }
    }
}

// e_t = relu(x_t @ encW^T + enc_b); wave w computes e cols [16w, 16w+16)
__device__ __forceinline__ void enc_proj(
    const half_t* __restrict__ xa, half_t* __restrict__ eOut,
    half8 encWf, float benc, int t, int w, int q, int l15) {
#pragma unroll
    for (int rt = 0; rt < 2; ++rt) {
        half8 af = *(const half8*)(xa + ((t * MTILE) + rt * 16 + l15) * XS + q * 8);
        float4_ a;
        a[0] = benc; a[1] = benc; a[2] = benc; a[3] = benc;
        a = __builtin_amdgcn_mfma_f32_16x16x32_f16(af, encWf, a, 0, 0, 0);
#pragma unroll
        for (int r = 0; r < 4; ++r) {
            float v = a[r];
            v = v > 0.f ? v : 0.f;
            eOut[(rt * 16 + q * 4 + r) * HS + w * 16 + l15] = (half_t)v;
        }
    }
}

__global__ __launch_bounds__(512, 2) void seq2seq_main_k(
    const float* __restrict__ x,
    const float* __restrict__ enc_b,
    const float* __restrict__ fc1_b,
    const float* __restrict__ fc2_W,
    const float* __restrict__ fc2_b,
    const half_t* __restrict__ wsh,
    const float* __restrict__ be,
    const float* __restrict__ bd,
    float* __restrict__ out) {
    __shared__ __align__(16) half_t xa[TSTEPS * MTILE * XS];   // 27648 B
    __shared__ __align__(16) half_t e_lds[2][MTILE * HS];      // 17920 B
    __shared__ __align__(16) half_t h_lds[2][MTILE * HS];      // 17920 B
    __shared__ float pred_lds[4][MTILE];                       // 512 B

    const int tid  = threadIdx.x;
    const int lane = tid & 63;
    const int w    = tid >> 6;        // wave 0..7
    const int q    = lane >> 4;
    const int l15  = lane & 15;
    const int n0   = blockIdx.x * MTILE;

    const half_t* WihE  = wsh;
    const half_t* WhhE  = wsh + 65536;
    const half_t* WihD  = wsh + 131072;
    const half_t* WhhD  = wsh + 196608;
    const half_t* encWp = wsh + 262144;
    const half_t* fc1p  = wsh + 266240;

    // per-wave biases: z col = g*128 + w*16 + l15
    float beR[4], bdR[4];
#pragma unroll
    for (int g = 0; g < 4; ++g) {
        int col = g * 128 + w * 16 + l15;
        beR[g] = be[col];
        bdR[g] = bd[col];
    }
    float benc = enc_b[w * 16 + l15];

    // stage ALL x timesteps for this tile into LDS (fp16), one-time.
    // 12 t * 32 rows * 4 chunks = 1536 units; 512 threads * 3.
#pragma unroll
    for (int it = 0; it < 3; ++it) {
        int unit = tid + it * 512;
        int t    = unit >> 7;
        int rest = unit & 127;
        int row  = rest >> 2;
        int c0   = (rest & 3) * 8;
        int n    = n0 + row;
        float4_ a0 = {0.f, 0.f, 0.f, 0.f}, a1 = {0.f, 0.f, 0.f, 0.f};
        if (n < NNODES) {
            const float* p = x + ((size_t)t * NNODES + n) * DIN + c0;
            a0 = *(const float4_*)p;
            a1 = *(const float4_*)(p + 4);
        }
        half8 hv;
        hv[0] = (half_t)a0[0]; hv[1] = (half_t)a0[1]; hv[2] = (half_t)a0[2]; hv[3] = (half_t)a0[3];
        hv[4] = (half_t)a1[0]; hv[5] = (half_t)a1[1]; hv[6] = (half_t)a1[2]; hv[7] = (half_t)a1[3];
        *(half8*)(xa + (t * MTILE + row) * XS + c0) = hv;
    }

    // zero initial h
    for (int i = tid; i < MTILE * HS; i += 512) h_lds[0][i] = (half_t)0.0f;

    float c_reg[2][4];
#pragma unroll
    for (int rt = 0; rt < 2; ++rt)
#pragma unroll
        for (int r = 0; r < 4; ++r) c_reg[rt][r] = 0.0f;

    // ---- encoder weights into registers (per-wave slice: 128 VGPRs) ----
    half8 wfi[4][4], wfh[4][4];
#pragma unroll
    for (int g = 0; g < 4; ++g)
#pragma unroll
        for (int kb = 0; kb < 4; ++kb) {
            int ct = g * 8 + w;
            wfi[g][kb] = *(const half8*)(WihE + ((size_t)(ct * 4 + kb) * 64 + lane) * 8);
            wfh[g][kb] = *(const half8*)(WhhE + ((size_t)(ct * 4 + kb) * 64 + lane) * 8);
        }
    half8 encWf = *(const half8*)(encWp + (size_t)w * 512 + lane * 8);

    __syncthreads();  // xa + h0 ready

    enc_proj(xa, e_lds[0], encWf, benc, 0, w, q, l15);
    __syncthreads();  // e0 ready

    int cur = 0;
    // ================= encoder: one barrier per step =================
    for (int t = 0; t < TSTEPS; ++t) {
        lstm_step32(e_lds[t & 1], h_lds[cur], h_lds[cur ^ 1], wfi, wfh, beR, c_reg, w, q, l15);
        if (t + 1 < TSTEPS)
            enc_proj(xa, e_lds[(t & 1) ^ 1], encWf, benc, t + 1, w, q, l15);
        __syncthreads();
        cur ^= 1;
    }

    // ---- decoder weights into the same registers; head params ----
#pragma unroll
    for (int g = 0; g < 4; ++g)
#pragma unroll
        for (int kb = 0; kb < 4; ++kb) {
            int ct = g * 8 + w;
            wfi[g][kb] = *(const half8*)(WihD + ((size_t)(ct * 4 + kb) * 64 + lane) * 8);
            wfh[g][kb] = *(const half8*)(WhhD + ((size_t)(ct * 4 + kb) * 64 + lane) * 8);
        }
    // head slice: wave w -> fc1 col-tile ct = w&3, row-half rtH = w>>2
    half8 fc1f[4];
#pragma unroll
    for (int kb = 0; kb < 4; ++kb)
        fc1f[kb] = *(const half8*)(fc1p + ((size_t)((w & 3) * 4 + kb) * 64 + lane) * 8);
    float bf1 = fc1_b[(w & 3) * 16 + l15];
    float wf2 = fc2_W[(w & 3) * 16 + l15];
    float bf2 = fc2_b[0];
    const int rtH = w >> 2;

    // d_in = final encoder h (fixed across decoder steps): copy h[cur] -> e_lds[0]
    for (int i = tid; i < MTILE * 64; i += 512) {
        int row = i >> 6, dc = i & 63;
        ((unsigned int*)(e_lds[0] + row * HS))[dc] =
            ((const unsigned int*)(h_lds[cur] + row * HS))[dc];
    }
    __syncthreads();

    // ================= decoder =================
    for (int s = 0; s < DECS; ++s) {
        lstm_step32(e_lds[0], h_lds[cur], h_lds[cur ^ 1], wfi, wfh, bdR, c_reg, w, q, l15);
        cur ^= 1;
        __syncthreads();  // new h ready
        // head: o64 = relu(h @ fc1^T + b1); pred = o64 @ fc2^T + b2
        float4_ hacc;
        hacc[0] = bf1; hacc[1] = bf1; hacc[2] = bf1; hacc[3] = bf1;
#pragma unroll
        for (int kb = 0; kb < 4; ++kb) {
            half8 af = *(const half8*)(h_lds[cur] + (rtH * 16 + l15) * HS + kb * 32 + q * 8);
            hacc = __builtin_amdgcn_mfma_f32_16x16x32_f16(af, fc1f[kb], hacc, 0, 0, 0);
        }
#pragma unroll
        for (int r = 0; r < 4; ++r) {
            float v = hacc[r];
            v = v > 0.f ? v : 0.f;
            v *= wf2;
            v += __shfl_xor(v, 1, 64);
            v += __shfl_xor(v, 2, 64);
            v += __shfl_xor(v, 4, 64);
            v += __shfl_xor(v, 8, 64);
            if (l15 == 0) pred_lds[w & 3][rtH * 16 + q * 4 + r] = v;
        }
        __syncthreads();
        if (tid < MTILE) {
            float sum = pred_lds[0][tid] + pred_lds[1][tid] + pred_lds[2][tid] + pred_lds[3][tid] + bf2;
            int n = n0 + tid;
            if (n < NNODES) out[(size_t)n * DECS + s] = sum;
        }
        // next head's pred_lds write is ordered behind the next lstm step's barrier
    }
}

extern "C" void kernel_launch(void* const* d_in, const int* in_sizes, int n_in,
                              void* d_out, int out_size, void* d_ws, size_t ws_size,
                              hipStream_t stream) {
    (void)in_sizes; (void)n_in; (void)out_size; (void)ws_size;
    const float* x     = (const float*)d_in[0];
    const float* enc_W = (const float*)d_in[1];
    const float* enc_b = (const float*)d_in[2];
    const float* Wih_e = (const float*)d_in[3];
    const float* Whh_e = (const float*)d_in[4];
    const float* bih_e = (const float*)d_in[5];
    const float* bhh_e = (const float*)d_in[6];
    const float* Wih_d = (const float*)d_in[7];
    const float* Whh_d = (const float*)d_in[8];
    const float* bih_d = (const float*)d_in[9];
    const float* bhh_d = (const float*)d_in[10];
    const float* fc1_W = (const float*)d_in[11];
    const float* fc1_b = (const float*)d_in[12];
    const float* fc2_W = (const float*)d_in[13];
    const float* fc2_b = (const float*)d_in[14];

    half_t* wsh = (half_t*)d_ws;
    float*  be  = (float*)((char*)d_ws + WS_FLOAT_OFF);
    float*  bd  = be + 512;

    pack_weights_k<<<256, 256, 0, stream>>>(Wih_e, wsh + 0,      128, 4, 65536);
    pack_weights_k<<<256, 256, 0, stream>>>(Whh_e, wsh + 65536,  128, 4, 65536);
    pack_weights_k<<<256, 256, 0, stream>>>(Wih_d, wsh + 131072, 128, 4, 65536);
    pack_weights_k<<<256, 256, 0, stream>>>(Whh_d, wsh + 196608, 128, 4, 65536);
    pack_weights_k<<<16,  256, 0, stream>>>(enc_W, wsh + 262144, 32,  1, 4096);
    pack_weights_k<<<32,  256, 0, stream>>>(fc1_W, wsh + 266240, 128, 4, 8192);
    prep_bias_k<<<2, 256, 0, stream>>>(bih_e, bhh_e, bih_d, bhh_d, be, bd);

    seq2seq_main_k<<<NTILES, 512, 0, stream>>>(x, enc_b, fc1_b, fc2_W, fc2_b,
                                               wsh, be, bd, (float*)d_out);
}

// Round 4
// 524.179 us; speedup vs baseline: 2.3194x; 1.8533x over previous
//
#include <hip/hip_runtime.h>

#define TSTEPS 12
#define NNODES 50000
#define DIN 32
#define HDIM 128
#define DECS 7
#define MTILE 64
#define NTILES ((NNODES + MTILE - 1) / MTILE)   // 782

#define HS 136   // halves per row for e/h buffers; 272B row stride -> bank step 4, 2-way max (free)
#define XS 36    // halves per row per timestep for x tile

typedef _Float16 half_t;
typedef _Float16 half8 __attribute__((ext_vector_type(8)));
typedef float float4_ __attribute__((ext_vector_type(4)));

// ---------------- workspace layout (halves then floats) ----------------
// halves: [0] WihE 65536 | [65536] WhhE | [131072] WihD | [196608] WhhD |
//         [262144] encW 4096 | [266240] fc1 8192   (total 274432 halves)
// floats at byte 548864: b_e[512], b_d[512]
#define WS_FLOAT_OFF 548864

// Fast activations: v_exp_f32 (2^x) + v_rcp_f32, ~1 ulp each — absmax headroom is 3.5x.
#if __has_builtin(__builtin_amdgcn_exp2f)
#define EXP2F __builtin_amdgcn_exp2f
#else
#define EXP2F exp2f
#endif
#if __has_builtin(__builtin_amdgcn_rcpf)
#define RCPF __builtin_amdgcn_rcpf
#else
#define RCPF(x) (1.0f / (x))
#endif

__device__ __forceinline__ float sigmoidf_(float x) {
    return RCPF(1.0f + EXP2F(-1.44269504f * x));
}
__device__ __forceinline__ float tanhf_(float x) {
    return fmaf(2.0f, RCPF(1.0f + EXP2F(-2.88539008f * x)), -1.0f);
}

// Pack fp32 [R,C] row-major into fragment-major fp16 (B-operand layout):
// dst[((ct*KB+kb)*64 + lane)*8 + j] = src[ct*16 + (lane&15)][kb*32 + (lane>>4)*8 + j]
__global__ void pack_weights_k(const float* __restrict__ src, half_t* __restrict__ dst,
                               int C, int KB, int total) {
    int tid = blockIdx.x * blockDim.x + threadIdx.x;
    if (tid >= total) return;
    int j    = tid & 7;
    int lane = (tid >> 3) & 63;
    int rest = tid >> 9;
    int kb   = rest % KB;
    int ct   = rest / KB;
    int row  = ct * 16 + (lane & 15);
    int col  = kb * 32 + ((lane >> 4) << 3) + j;
    dst[tid] = (half_t)src[row * C + col];
}

__global__ void prep_bias_k(const float* __restrict__ bih_e, const float* __restrict__ bhh_e,
                            const float* __restrict__ bih_d, const float* __restrict__ bhh_d,
                            float* __restrict__ be, float* __restrict__ bd) {
    int tid = blockIdx.x * blockDim.x + threadIdx.x;
    if (tid < 512) {
        be[tid] = bih_e[tid] + bhh_e[tid];
        bd[tid] = bih_d[tid] + bhh_d[tid];
    }
}

// LSTM step for a 64-node tile, 8 waves, H split 8-way (wave w owns h-cols [16w,16w+16)).
// rt OUTERMOST: per rt only 16 acc regs live; activation VALU of rt overlaps the
// independent MFMA chain of rt+1 in the same instruction stream (matrix/VALU pipe overlap).
__device__ __forceinline__ void lstm_step64(
    const half_t* __restrict__ eA, const half_t* __restrict__ hA, half_t* __restrict__ hOut,
    const half8 (&wfi)[4][4], const half8 (&wfh)[4][4],
    const float bR[4], float cS[4][4],
    int w, int q, int l15) {
#pragma unroll
    for (int rt = 0; rt < 4; ++rt) {
        float4_ acc[4];
#pragma unroll
        for (int g = 0; g < 4; ++g) {
            float b = bR[g];
            acc[g][0] = b; acc[g][1] = b; acc[g][2] = b; acc[g][3] = b;
        }
#pragma unroll
        for (int kb = 0; kb < 4; ++kb) {
            half8 ae = *(const half8*)(eA + (rt * 16 + l15) * HS + kb * 32 + q * 8);
            half8 ah = *(const half8*)(hA + (rt * 16 + l15) * HS + kb * 32 + q * 8);
#pragma unroll
            for (int g = 0; g < 4; ++g) {
                acc[g] = __builtin_amdgcn_mfma_f32_16x16x32_f16(ae, wfi[g][kb], acc[g], 0, 0, 0);
                acc[g] = __builtin_amdgcn_mfma_f32_16x16x32_f16(ah, wfh[g][kb], acc[g], 0, 0, 0);
            }
        }
        // C-layout: row = rt*16 + q*4 + r, col (within H) = w*16 + l15
#pragma unroll
        for (int r = 0; r < 4; ++r) {
            float iv = sigmoidf_(acc[0][r]);
            float fv = sigmoidf_(acc[1][r]);
            float gv = tanhf_(acc[2][r]);
            float ov = sigmoidf_(acc[3][r]);
            float c  = fv * cS[rt][r] + iv * gv;
            cS[rt][r] = c;
            float h = ov * tanhf_(c);
            hOut[(rt * 16 + q * 4 + r) * HS + w * 16 + l15] = (half_t)h;
        }
    }
}

// e_t = relu(x_t @ encW^T + enc_b); wave w computes e cols [16w, 16w+16)
__device__ __forceinline__ void enc_proj(
    const half_t* __restrict__ xa, half_t* __restrict__ eOut,
    half8 encWf, float benc, int t, int w, int q, int l15) {
#pragma unroll
    for (int rt = 0; rt < 4; ++rt) {
        half8 af = *(const half8*)(xa + ((t * MTILE) + rt * 16 + l15) * XS + q * 8);
        float4_ a;
        a[0] = benc; a[1] = benc; a[2] = benc; a[3] = benc;
        a = __builtin_amdgcn_mfma_f32_16x16x32_f16(af, encWf, a, 0, 0, 0);
#pragma unroll
        for (int r = 0; r < 4; ++r) {
            float v = a[r];
            v = v > 0.f ? v : 0.f;
            eOut[(rt * 16 + q * 4 + r) * HS + w * 16 + l15] = (half_t)v;
        }
    }
}

__global__ __launch_bounds__(512, 2) void seq2seq_main_k(
    const float* __restrict__ x,
    const float* __restrict__ enc_b,
    const float* __restrict__ fc1_b,
    const float* __restrict__ fc2_W,
    const float* __restrict__ fc2_b,
    const half_t* __restrict__ wsh,
    const float* __restrict__ be,
    const float* __restrict__ bd,
    float* __restrict__ out) {
    __shared__ __align__(16) half_t xa[TSTEPS * MTILE * XS];   // 55296 B
    __shared__ __align__(16) half_t e_lds[2][MTILE * HS];      // 34816 B
    __shared__ __align__(16) half_t h_lds[2][MTILE * HS];      // 34816 B
    __shared__ float pred_lds[4][MTILE];                       // 1024 B

    const int tid  = threadIdx.x;
    const int lane = tid & 63;
    const int w    = tid >> 6;        // wave 0..7
    const int q    = lane >> 4;
    const int l15  = lane & 15;
    const int n0   = blockIdx.x * MTILE;

    const half_t* WihE  = wsh;
    const half_t* WhhE  = wsh + 65536;
    const half_t* WihD  = wsh + 131072;
    const half_t* WhhD  = wsh + 196608;
    const half_t* encWp = wsh + 262144;
    const half_t* fc1p  = wsh + 266240;

    // per-wave biases: z col = g*128 + w*16 + l15
    float beR[4], bdR[4];
#pragma unroll
    for (int g = 0; g < 4; ++g) {
        int col = g * 128 + w * 16 + l15;
        beR[g] = be[col];
        bdR[g] = bd[col];
    }
    float benc = enc_b[w * 16 + l15];

    // stage ALL x timesteps for this tile into LDS (fp16), one-time.
    // 12 t * 64 rows * 4 chunks = 3072 units; 512 threads * 6.
#pragma unroll
    for (int it = 0; it < 6; ++it) {
        int unit = tid + it * 512;
        int t    = unit >> 8;
        int rest = unit & 255;
        int row  = rest >> 2;
        int c0   = (rest & 3) * 8;
        int n    = n0 + row;
        float4_ a0 = {0.f, 0.f, 0.f, 0.f}, a1 = {0.f, 0.f, 0.f, 0.f};
        if (n < NNODES) {
            const float* p = x + ((size_t)t * NNODES + n) * DIN + c0;
            a0 = *(const float4_*)p;
            a1 = *(const float4_*)(p + 4);
        }
        half8 hv;
        hv[0] = (half_t)a0[0]; hv[1] = (half_t)a0[1]; hv[2] = (half_t)a0[2]; hv[3] = (half_t)a0[3];
        hv[4] = (half_t)a1[0]; hv[5] = (half_t)a1[1]; hv[6] = (half_t)a1[2]; hv[7] = (half_t)a1[3];
        *(half8*)(xa + (t * MTILE + row) * XS + c0) = hv;
    }

    // zero initial h
    for (int i = tid; i < MTILE * HS; i += 512) h_lds[0][i] = (half_t)0.0f;

    float c_reg[4][4];
#pragma unroll
    for (int rt = 0; rt < 4; ++rt)
#pragma unroll
        for (int r = 0; r < 4; ++r) c_reg[rt][r] = 0.0f;

    // ---- encoder weights into registers (per-wave slice: 128 VGPRs) ----
    half8 wfi[4][4], wfh[4][4];
#pragma unroll
    for (int g = 0; g < 4; ++g)
#pragma unroll
        for (int kb = 0; kb < 4; ++kb) {
            int ct = g * 8 + w;
            wfi[g][kb] = *(const half8*)(WihE + ((size_t)(ct * 4 + kb) * 64 + lane) * 8);
            wfh[g][kb] = *(const half8*)(WhhE + ((size_t)(ct * 4 + kb) * 64 + lane) * 8);
        }
    half8 encWf = *(const half8*)(encWp + (size_t)w * 512 + lane * 8);

    __syncthreads();  // xa + h0 ready

    enc_proj(xa, e_lds[0], encWf, benc, 0, w, q, l15);
    __syncthreads();  // e0 ready

    int cur = 0;
    // ================= encoder: one barrier per step =================
    for (int t = 0; t < TSTEPS; ++t) {
        lstm_step64(e_lds[t & 1], h_lds[cur], h_lds[cur ^ 1], wfi, wfh, beR, c_reg, w, q, l15);
        if (t + 1 < TSTEPS)
            enc_proj(xa, e_lds[(t & 1) ^ 1], encWf, benc, t + 1, w, q, l15);
        __syncthreads();
        cur ^= 1;
    }

    // ---- decoder weights into the same registers; head params ----
#pragma unroll
    for (int g = 0; g < 4; ++g)
#pragma unroll
        for (int kb = 0; kb < 4; ++kb) {
            int ct = g * 8 + w;
            wfi[g][kb] = *(const half8*)(WihD + ((size_t)(ct * 4 + kb) * 64 + lane) * 8);
            wfh[g][kb] = *(const half8*)(WhhD + ((size_t)(ct * 4 + kb) * 64 + lane) * 8);
        }
    // head slice: wave w -> fc1 col-tile ct = w&3, row-tiles {2*(w>>2), 2*(w>>2)+1}
    half8 fc1f[4];
#pragma unroll
    for (int kb = 0; kb < 4; ++kb)
        fc1f[kb] = *(const half8*)(fc1p + ((size_t)((w & 3) * 4 + kb) * 64 + lane) * 8);
    float bf1 = fc1_b[(w & 3) * 16 + l15];
    float wf2 = fc2_W[(w & 3) * 16 + l15];
    float bf2 = fc2_b[0];
    const int rtH = (w >> 2) * 2;

    // d_in = final encoder h (fixed across decoder steps): copy h[cur] -> e_lds[0]
    for (int i = tid; i < MTILE * 64; i += 512) {
        int row = i >> 6, dc = i & 63;
        ((unsigned int*)(e_lds[0] + row * HS))[dc] =
            ((const unsigned int*)(h_lds[cur] + row * HS))[dc];
    }
    __syncthreads();

    // ================= decoder =================
    for (int s = 0; s < DECS; ++s) {
        lstm_step64(e_lds[0], h_lds[cur], h_lds[cur ^ 1], wfi, wfh, bdR, c_reg, w, q, l15);
        cur ^= 1;
        __syncthreads();  // new h ready
        // head: o64 = relu(h @ fc1^T + b1); pred = o64 @ fc2^T + b2
#pragma unroll
        for (int rp = 0; rp < 2; ++rp) {
            int rt = rtH + rp;
            float4_ hacc;
            hacc[0] = bf1; hacc[1] = bf1; hacc[2] = bf1; hacc[3] = bf1;
#pragma unroll
            for (int kb = 0; kb < 4; ++kb) {
                half8 af = *(const half8*)(h_lds[cur] + (rt * 16 + l15) * HS + kb * 32 + q * 8);
                hacc = __builtin_amdgcn_mfma_f32_16x16x32_f16(af, fc1f[kb], hacc, 0, 0, 0);
            }
#pragma unroll
            for (int r = 0; r < 4; ++r) {
                float v = hacc[r];
                v = v > 0.f ? v : 0.f;
                v *= wf2;
                v += __shfl_xor(v, 1, 64);
                v += __shfl_xor(v, 2, 64);
                v += __shfl_xor(v, 4, 64);
                v += __shfl_xor(v, 8, 64);
                if (l15 == 0) pred_lds[w & 3][rt * 16 + q * 4 + r] = v;
            }
        }
        __syncthreads();
        if (tid < MTILE) {
            float sum = pred_lds[0][tid] + pred_lds[1][tid] + pred_lds[2][tid] + pred_lds[3][tid] + bf2;
            int n = n0 + tid;
            if (n < NNODES) out[(size_t)n * DECS + s] = sum;
        }
        // next head's pred_lds write is ordered behind the next lstm step's barrier
    }
}

extern "C" void kernel_launch(void* const* d_in, const int* in_sizes, int n_in,
                              void* d_out, int out_size, void* d_ws, size_t ws_size,
                              hipStream_t stream) {
    (void)in_sizes; (void)n_in; (void)out_size; (void)ws_size;
    const float* x     = (const float*)d_in[0];
    const float* enc_W = (const float*)d_in[1];
    const float* enc_b = (const float*)d_in[2];
    const float* Wih_e = (const float*)d_in[3];
    const float* Whh_e = (const float*)d_in[4];
    const float* bih_e = (const float*)d_in[5];
    const float* bhh_e = (const float*)d_in[6];
    const float* Wih_d = (const float*)d_in[7];
    const float* Whh_d = (const float*)d_in[8];
    const float* bih_d = (const float*)d_in[9];
    const float* bhh_d = (const float*)d_in[10];
    const float* fc1_W = (const float*)d_in[11];
    const float* fc1_b = (const float*)d_in[12];
    const float* fc2_W = (const float*)d_in[13];
    const float* fc2_b = (const float*)d_in[14];

    half_t* wsh = (half_t*)d_ws;
    float*  be  = (float*)((char*)d_ws + WS_FLOAT_OFF);
    float*  bd  = be + 512;

    pack_weights_k<<<256, 256, 0, stream>>>(Wih_e, wsh + 0,      128, 4, 65536);
    pack_weights_k<<<256, 256, 0, stream>>>(Whh_e, wsh + 65536,  128, 4, 65536);
    pack_weights_k<<<256, 256, 0, stream>>>(Wih_d, wsh + 131072, 128, 4, 65536);
    pack_weights_k<<<256, 256, 0, stream>>>(Whh_d, wsh + 196608, 128, 4, 65536);
    pack_weights_k<<<16,  256, 0, stream>>>(enc_W, wsh + 262144, 32,  1, 4096);
    pack_weights_k<<<32,  256, 0, stream>>>(fc1_W, wsh + 266240, 128, 4, 8192);
    prep_bias_k<<<2, 256, 0, stream>>>(bih_e, bhh_e, bih_d, bhh_d, be, bd);

    seq2seq_main_k<<<NTILES, 512, 0, stream>>>(x, enc_b, fc1_b, fc2_W, fc2_b,
                                               wsh, be, bd, (float*)d_out);
}